// Round 3
// baseline (845.423 us; speedup 1.0000x reference)
//
#include <hip/hip_runtime.h>

typedef unsigned short u16;
typedef short bf16x8 __attribute__((ext_vector_type(8)));
typedef float f32x4 __attribute__((ext_vector_type(4)));

__device__ __forceinline__ float bf2f(u16 s) {
    union { unsigned u; float f; } v;
    v.u = ((unsigned)s) << 16;
    return v.f;
}
__device__ __forceinline__ u16 f2bf(float f) {
    union { float f; unsigned u; } v;
    v.f = f;
    unsigned r = v.u + 0x7fffu + ((v.u >> 16) & 1u);  // RNE
    return (u16)(r >> 16);
}

#define GLD16(gp, lp)                                                  \
    __builtin_amdgcn_global_load_lds(                                  \
        (__attribute__((address_space(1))) void*)(gp),                 \
        (__attribute__((address_space(3))) void*)(lp), 16, 0, 0)

// ---------------------------------------------------------------------------
// Detect whether d_in[0] is f32 (flag=1) or bf16 (flag=0).
// bf16 N(0,1): exponent field <= 0x81 always. f32-as-u16: low halves are
// ~uniform -> ~22% of samples have exp field >= 0x90.
// ---------------------------------------------------------------------------
__global__ __launch_bounds__(256) void detect_kernel(
    const u16* __restrict__ src, int* __restrict__ flag)
{
    __shared__ int red[4];
    const int tid = threadIdx.x;
    int cnt = 0;
    for (int j = 0; j < 64; j++) {
        const u16 v = src[tid * 64 + j];
        const int e = (v >> 7) & 0xFF;
        cnt += (e >= 0x90) ? 1 : 0;
    }
#pragma unroll
    for (int m = 1; m < 64; m <<= 1) cnt += __shfl_xor(cnt, m);
    if ((tid & 63) == 0) red[tid >> 6] = cnt;
    __syncthreads();
    if (tid == 0) {
        const int total = red[0] + red[1] + red[2] + red[3];
        flag[0] = (total > 1024) ? 1 : 0;  // >6.25% of 16384 samples
    }
}

// ---------------------------------------------------------------------------
// Normalize input to bf16: copy (flag=0) or f32->bf16 (flag=1). 8 elems/thread.
// ---------------------------------------------------------------------------
__global__ __launch_bounds__(256) void convert_kernel(
    const void* __restrict__ src, u16* __restrict__ dst, long long n,
    const int* __restrict__ flag)
{
    const long long i = ((long long)blockIdx.x * 256 + threadIdx.x) * 8;
    if (i >= n) return;
    union { uint4 q; u16 u[8]; } o;
    if (flag[0]) {
        const float* s = (const float*)src + i;
        const float4 a = *(const float4*)s;
        const float4 b = *(const float4*)(s + 4);
        o.u[0] = f2bf(a.x); o.u[1] = f2bf(a.y);
        o.u[2] = f2bf(a.z); o.u[3] = f2bf(a.w);
        o.u[4] = f2bf(b.x); o.u[5] = f2bf(b.y);
        o.u[6] = f2bf(b.z); o.u[7] = f2bf(b.w);
    } else {
        o.q = *(const uint4*)((const u16*)src + i);
    }
    *(uint4*)(dst + i) = o.q;
}

// ---------------------------------------------------------------------------
// GEMM: C[M,N](bf16) = scale * (A[M,K] . B[N,K]^T) + bias
// bias_mode: 0 none, 1 bias[col], 2 bias[row]. Batched via grid.z.
// Block 256 = 4 waves, each 64x64 via 4x4 MFMA 16x16x32 bf16.
// ---------------------------------------------------------------------------
__global__ __launch_bounds__(256) void gemm_bt_kernel(
    const u16* __restrict__ A, const u16* __restrict__ B,
    u16* __restrict__ C, const u16* __restrict__ bias,
    float scale, int bias_mode,
    int lda, int ldb, int ldc, int K,
    long long sA, long long sB, long long sC)
{
    __shared__ alignas(16) u16 As[128 * 32];
    __shared__ alignas(16) u16 Bs[128 * 32];

    const int tid  = threadIdx.x;
    const int lane = tid & 63;
    const int wave = tid >> 6;
    const int wm   = wave & 1;
    const int wn   = wave >> 1;
    const int z    = blockIdx.z;
    A += (long long)z * sA;
    B += (long long)z * sB;
    C += (long long)z * sC;
    const int bm = blockIdx.y, bn = blockIdx.x;

    const int srow = tid >> 2;
    const int scol = (tid & 3) << 3;
    const u16* ag = A + (long long)(bm * 128 + srow) * lda + scol;
    const u16* bg = B + (long long)(bn * 128 + srow) * ldb + scol;
    const long long a64 = (long long)64 * lda;
    const long long b64 = (long long)64 * ldb;
    u16* as0 = As + wave * 512;
    u16* as1 = As + 2048 + wave * 512;
    u16* bs0 = Bs + wave * 512;
    u16* bs1 = Bs + 2048 + wave * 512;

    f32x4 acc[4][4];
#pragma unroll
    for (int i = 0; i < 4; i++)
#pragma unroll
        for (int j = 0; j < 4; j++) {
            acc[i][j][0] = 0.f; acc[i][j][1] = 0.f;
            acc[i][j][2] = 0.f; acc[i][j][3] = 0.f;
        }

    const int fr = lane & 15, fq = lane >> 4;
    const u16* aRead = As + (wm * 64 + fr) * 32 + fq * 8;
    const u16* bRead = Bs + (wn * 64 + fr) * 32 + fq * 8;

    for (int k0 = 0; k0 < K; k0 += 32) {
        GLD16(ag + k0,       as0);
        GLD16(ag + k0 + a64, as1);
        GLD16(bg + k0,       bs0);
        GLD16(bg + k0 + b64, bs1);
        __syncthreads();

        bf16x8 af[4], bfr[4];
#pragma unroll
        for (int i = 0; i < 4; i++) {
            af[i]  = *(const bf16x8*)(aRead + i * 16 * 32);
            bfr[i] = *(const bf16x8*)(bRead + i * 16 * 32);
        }
#pragma unroll
        for (int i = 0; i < 4; i++)
#pragma unroll
            for (int j = 0; j < 4; j++)
                acc[i][j] = __builtin_amdgcn_mfma_f32_16x16x32_bf16(
                    af[i], bfr[j], acc[i][j], 0, 0, 0);
        __syncthreads();
    }

    const int crow0 = bm * 128 + wm * 64 + fq * 4;
    const int ccol0 = bn * 128 + wn * 64 + fr;
#pragma unroll
    for (int i = 0; i < 4; i++) {
#pragma unroll
        for (int r = 0; r < 4; r++) {
            const int row = crow0 + i * 16 + r;
            const float bvr = (bias_mode == 2) ? bf2f(bias[row]) : 0.0f;
#pragma unroll
            for (int j = 0; j < 4; j++) {
                const int col = ccol0 + j * 16;
                const float bv = (bias_mode == 1) ? bf2f(bias[col]) : bvr;
                C[(long long)row * ldc + col] = f2bf(acc[i][j][r] * scale + bv);
            }
        }
    }
}

// ---------------------------------------------------------------------------
// In-place row softmax over 1024 bf16 elements. One wave per row.
// ---------------------------------------------------------------------------
__global__ __launch_bounds__(256) void softmax_kernel(u16* __restrict__ S)
{
    const int tid = threadIdx.x, lane = tid & 63, wave = tid >> 6;
    const long long row = (long long)blockIdx.x * 4 + wave;
    u16* p = S + row * 1024 + lane * 16;
    union { uint4 q[2]; u16 u[16]; } d;
    d.q[0] = *(const uint4*)p;
    d.q[1] = *(const uint4*)(p + 8);
    float x[16];
    float mx = -1e30f;
#pragma unroll
    for (int j = 0; j < 16; j++) { x[j] = bf2f(d.u[j]); mx = fmaxf(mx, x[j]); }
#pragma unroll
    for (int m = 1; m < 64; m <<= 1) mx = fmaxf(mx, __shfl_xor(mx, m));
    float s = 0.f;
#pragma unroll
    for (int j = 0; j < 16; j++) { x[j] = __expf(x[j] - mx); s += x[j]; }
#pragma unroll
    for (int m = 1; m < 64; m <<= 1) s += __shfl_xor(s, m);
    const float inv = 1.0f / s;
#pragma unroll
    for (int j = 0; j < 16; j++) d.u[j] = f2bf(x[j] * inv);
    *(uint4*)p = d.q[0];
    *(uint4*)(p + 8) = d.q[1];
}

// ---------------------------------------------------------------------------
// LayerNorm(obj + I) * g + b -> out (f32 or bf16 per flag). One block per row.
// obj/I pre-offset by host; outOff is in elements of d_out.
// ---------------------------------------------------------------------------
__global__ __launch_bounds__(256) void ln_kernel(
    const u16* __restrict__ obj, const u16* __restrict__ gam,
    const u16* __restrict__ bet, const u16* __restrict__ I,
    void* __restrict__ outv, long long outOff, const int* __restrict__ flag)
{
    __shared__ float red[8];
    const int tid = threadIdx.x, lane = tid & 63, wave = tid >> 6;
    const long long base = (long long)blockIdx.x * 1024;
    const int c = tid * 4;
    union { uint2 q; u16 u[4]; } ov, iv, gv, bv;
    ov.q = *(const uint2*)(obj + base + c);
    iv.q = *(const uint2*)(I + base + c);
    float x[4], s = 0.f, sq = 0.f;
#pragma unroll
    for (int j = 0; j < 4; j++) {
        x[j] = bf2f(ov.u[j]) + bf2f(iv.u[j]);
        s += x[j]; sq += x[j] * x[j];
    }
#pragma unroll
    for (int m = 1; m < 64; m <<= 1) {
        s += __shfl_xor(s, m);
        sq += __shfl_xor(sq, m);
    }
    if (lane == 0) { red[wave] = s; red[4 + wave] = sq; }
    __syncthreads();
    s = red[0] + red[1] + red[2] + red[3];
    sq = red[4] + red[5] + red[6] + red[7];
    const float mu = s * (1.0f / 1024.0f);
    const float var = fmaxf(sq * (1.0f / 1024.0f) - mu * mu, 0.0f);
    const float rs = rsqrtf(var + 1e-5f);
    gv.q = *(const uint2*)(gam + c);
    bv.q = *(const uint2*)(bet + c);
    float y[4];
#pragma unroll
    for (int j = 0; j < 4; j++)
        y[j] = (x[j] - mu) * rs * bf2f(gv.u[j]) + bf2f(bv.u[j]);
    if (flag[0]) {
        float4 w; w.x = y[0]; w.y = y[1]; w.z = y[2]; w.w = y[3];
        *(float4*)((float*)outv + outOff + base + c) = w;
    } else {
        union { uint2 q; u16 u[4]; } wv;
#pragma unroll
        for (int j = 0; j < 4; j++) wv.u[j] = f2bf(y[j]);
        *(uint2*)((u16*)outv + outOff + base + c) = wv.q;
    }
}

// ---------------------------------------------------------------------------
extern "C" void kernel_launch(void* const* d_in, const int* in_sizes, int n_in,
                              void* d_out, int out_size, void* d_ws, size_t ws_size,
                              hipStream_t stream)
{
    u16* ws = (u16*)d_ws;
    int* flag = (int*)d_ws;              // header: first 64 bytes
    const dim3 blk(256);
    const float scale = 0.03125f;        // 1024^-0.5
    const long long Eobj = 16777216;     // 8*2048*1024
    const long long Ekv  = 8388608;      // 8*1024*1024
    const long long sQ = 2048LL * 1024, sK = 1024LL * 1024;

    detect_kernel<<<dim3(1), blk, 0, stream>>>((const u16*)d_in[0], flag);

    // bump-allocate converted inputs after 64B header
    const size_t wsElems = ws_size / 2;
    long long cur = 32;
    u16* cIn[15];
    long long convTotal = 0;
    for (int i = 0; i < 15 && i < n_in; i++) convTotal += in_sizes[i];
    const bool canConv = wsElems >= (size_t)(32 + convTotal + 8388608);
    if (canConv) {
        for (int i = 0; i < 15 && i < n_in; i++) {
            cIn[i] = ws + cur;
            cur += in_sizes[i];
            const long long n = in_sizes[i];
            const int grid = (int)((n / 8 + 255) / 256);
            convert_kernel<<<dim3(grid), blk, 0, stream>>>(d_in[i], cIn[i], n, flag);
        }
    } else {
        for (int i = 0; i < 15 && i < n_in; i++) cIn[i] = (u16*)d_in[i];
    }
    const u16* obj = cIn[0];  const u16* sub = cIn[1];  const u16* scene = cIn[2];
    const u16* W_q = cIn[3];  const u16* b_q = cIn[4];
    const u16* W_sk = cIn[5]; const u16* b_sk = cIn[6];
    const u16* W_sv = cIn[7]; const u16* b_sv = cIn[8];
    const u16* W_ek = cIn[9]; const u16* b_ek = cIn[10];
    const u16* W_ev = cIn[11]; const u16* b_ev = cIn[12];
    const u16* ln_g = cIn[13]; const u16* ln_b = cIn[14];

    const bool planA = wsElems >= (size_t)(cur + Eobj + Ekv + Ekv + Eobj + Eobj);

    if (planA) {
        u16* Q  = ws + cur;
        u16* Kb = Q + Eobj;
        u16* VT = Kb + Ekv;
        u16* S  = VT + Ekv;
        u16* O  = S + Eobj;

        gemm_bt_kernel<<<dim3(8, 128, 1), blk, 0, stream>>>(
            obj, W_q, Q, b_q, 1.0f, 1, 1024, 1024, 1024, 1024, 0, 0, 0);

        for (int a = 0; a < 2; a++) {
            const u16* X  = a ? scene : sub;
            const u16* Wk = a ? W_ek : W_sk;
            const u16* bk = a ? b_ek : b_sk;
            const u16* Wv = a ? W_ev : W_sv;
            const u16* bv = a ? b_ev : b_sv;

            gemm_bt_kernel<<<dim3(8, 64, 1), blk, 0, stream>>>(
                X, Wk, Kb, bk, 1.0f, 1, 1024, 1024, 1024, 1024, 0, 0, 0);
            // VT[p][z*1024+s] = V_z[s][p] = Wv[p,:].X_z[s,:] + bv[p]
            gemm_bt_kernel<<<dim3(64, 8, 1), blk, 0, stream>>>(
                Wv, X, VT, bv, 1.0f, 2, 1024, 1024, 8192, 1024, 0, 0, 0);
            gemm_bt_kernel<<<dim3(8, 16, 8), blk, 0, stream>>>(
                Q, Kb, S, nullptr, scale, 0, 1024, 1024, 1024, 1024, sQ, sK, sQ);
            softmax_kernel<<<dim3(4096), blk, 0, stream>>>(S);
            gemm_bt_kernel<<<dim3(8, 16, 8), blk, 0, stream>>>(
                S, VT, O, nullptr, 1.0f, 0, 1024, 8192, 1024, 1024, sQ, 1024, sQ);
            ln_kernel<<<dim3(16384), blk, 0, stream>>>(
                obj, ln_g, ln_b, O, d_out, (long long)a * Eobj, flag);
        }
    } else {
        // per-batch plan: 8.39M elems of pipeline scratch
        u16* Qb = ws + cur;              // 2M
        u16* Kb = Qb + 2097152;          // 1M
        u16* VT = Kb + 1048576;          // 1M
        u16* S  = VT + 1048576;          // 2M
        u16* O  = S + 2097152;           // 2M

        for (int a = 0; a < 2; a++) {
            const u16* X  = a ? scene : sub;
            const u16* Wk = a ? W_ek : W_sk;
            const u16* bk = a ? b_ek : b_sk;
            const u16* Wv = a ? W_ev : W_sv;
            const u16* bv = a ? b_ev : b_sv;

            for (int z = 0; z < 8; z++) {
                const u16* objz = obj + (long long)z * sQ;
                const u16* Xz   = X + (long long)z * sK;
                gemm_bt_kernel<<<dim3(8, 16, 1), blk, 0, stream>>>(
                    objz, W_q, Qb, b_q, 1.0f, 1, 1024, 1024, 1024, 1024, 0, 0, 0);
                gemm_bt_kernel<<<dim3(8, 8, 1), blk, 0, stream>>>(
                    Xz, Wk, Kb, bk, 1.0f, 1, 1024, 1024, 1024, 1024, 0, 0, 0);
                gemm_bt_kernel<<<dim3(8, 8, 1), blk, 0, stream>>>(
                    Wv, Xz, VT, bv, 1.0f, 2, 1024, 1024, 1024, 1024, 0, 0, 0);
                gemm_bt_kernel<<<dim3(8, 16, 1), blk, 0, stream>>>(
                    Qb, Kb, S, nullptr, scale, 0, 1024, 1024, 1024, 1024, 0, 0, 0);
                softmax_kernel<<<dim3(512), blk, 0, stream>>>(S);
                gemm_bt_kernel<<<dim3(8, 16, 1), blk, 0, stream>>>(
                    S, VT, O, nullptr, 1.0f, 0, 1024, 1024, 1024, 1024, 0, 0, 0);
                ln_kernel<<<dim3(2048), blk, 0, stream>>>(
                    objz, ln_g, ln_b, O, d_out,
                    (long long)a * Eobj + (long long)z * sQ, flag);
            }
        }
    }

    (void)out_size;
}

// Round 4
// 814.344 us; speedup vs baseline: 1.0382x; 1.0382x over previous
//
#include <hip/hip_runtime.h>

typedef unsigned short u16;
typedef short bf16x8 __attribute__((ext_vector_type(8)));
typedef float f32x4 __attribute__((ext_vector_type(4)));

__device__ __forceinline__ float bf2f(u16 s) {
    union { unsigned u; float f; } v;
    v.u = ((unsigned)s) << 16;
    return v.f;
}
__device__ __forceinline__ u16 f2bf(float f) {
    union { float f; unsigned u; } v;
    v.f = f;
    unsigned r = v.u + 0x7fffu + ((v.u >> 16) & 1u);  // RNE
    return (u16)(r >> 16);
}

#define GLD16(gp, lp)                                                  \
    __builtin_amdgcn_global_load_lds(                                  \
        (__attribute__((address_space(1))) void*)(gp),                 \
        (__attribute__((address_space(3))) void*)(lp), 16, 0, 0)

// ---------------------------------------------------------------------------
// Detect whether d_in[0] is f32 (flag=1) or bf16 (flag=0).
// ---------------------------------------------------------------------------
__global__ __launch_bounds__(256) void detect_kernel(
    const u16* __restrict__ src, int* __restrict__ flag)
{
    __shared__ int red[4];
    const int tid = threadIdx.x;
    int cnt = 0;
    for (int j = 0; j < 64; j++) {
        const u16 v = src[tid * 64 + j];
        const int e = (v >> 7) & 0xFF;
        cnt += (e >= 0x90) ? 1 : 0;
    }
#pragma unroll
    for (int m = 1; m < 64; m <<= 1) cnt += __shfl_xor(cnt, m);
    if ((tid & 63) == 0) red[tid >> 6] = cnt;
    __syncthreads();
    if (tid == 0) {
        const int total = red[0] + red[1] + red[2] + red[3];
        flag[0] = (total > 1024) ? 1 : 0;
    }
}

// ---------------------------------------------------------------------------
// Single merged conversion: all 15 inputs -> contiguous bf16 region in ws.
// Segment sizes are all multiples of 8, so an 8-elem chunk never straddles.
// ---------------------------------------------------------------------------
struct ConvArgs {
    const void* src[15];
    long long   off[16];   // cumulative element offsets in dst (off[15]=total)
};

__global__ __launch_bounds__(256) void convert_all_kernel(
    ConvArgs a, u16* __restrict__ dst, const int* __restrict__ flag)
{
    const long long i = ((long long)blockIdx.x * 256 + threadIdx.x) * 8;
    if (i >= a.off[15]) return;
    int s = 0;
#pragma unroll
    for (int t = 1; t < 15; t++) s += (i >= a.off[t]) ? 1 : 0;
    const long long local = i - a.off[s];
    union { uint4 q; u16 u[8]; } o;
    if (flag[0]) {
        const float* sp = (const float*)a.src[s] + local;
        const float4 x = *(const float4*)sp;
        const float4 y = *(const float4*)(sp + 4);
        o.u[0] = f2bf(x.x); o.u[1] = f2bf(x.y);
        o.u[2] = f2bf(x.z); o.u[3] = f2bf(x.w);
        o.u[4] = f2bf(y.x); o.u[5] = f2bf(y.y);
        o.u[6] = f2bf(y.z); o.u[7] = f2bf(y.w);
    } else {
        o.q = *(const uint4*)((const u16*)a.src[s] + local);
    }
    *(uint4*)(dst + i) = o.q;
}

// ---------------------------------------------------------------------------
// GEMM: C[M,N](bf16) = scale * (A[M,K] . B[N,K]^T) + bias
// bias_mode: 0 none, 1 bias[col], 2 bias[row]. Batched via grid.z.
// Block 256 = 4 waves, each 64x64 via 4x4 MFMA 16x16x32 bf16.
// BK=64 (32 MFMAs per barrier pair); LDS 2x16KB; XOR-swizzled col-blocks:
// LDS[row][cb] holds global col-block cb ^ (row&7)  (conflict-free reads).
// ---------------------------------------------------------------------------
__global__ __launch_bounds__(256) void gemm_bt_kernel(
    const u16* __restrict__ A, const u16* __restrict__ B,
    u16* __restrict__ C, const u16* __restrict__ bias,
    float scale, int bias_mode,
    int lda, int ldb, int ldc, int K,
    long long sA, long long sB, long long sC)
{
    __shared__ alignas(16) u16 As[128 * 64];  // 16 KB, [128 rows][64 cols]
    __shared__ alignas(16) u16 Bs[128 * 64];

    const int tid  = threadIdx.x;
    const int lane = tid & 63;
    const int wave = tid >> 6;
    const int wm   = wave & 1;
    const int wn   = wave >> 1;
    const int z    = blockIdx.z;
    A += (long long)z * sA;
    B += (long long)z * sB;
    C += (long long)z * sC;
    const int bm = blockIdx.y, bn = blockIdx.x;

    // staging: wave covers slabs wave*4..wave*4+3, each slab = 8 rows x 64 cols
    // lane -> row lane>>3 within slab, col-block (lane&7) XOR row (swizzle)
    const int srow = lane >> 3;                 // 0..7
    const int scb  = (lane & 7) ^ srow;         // swizzled global col-block
    const long long arow = (long long)(bm * 128 + wave * 32 + srow);
    const long long brow = (long long)(bn * 128 + wave * 32 + srow);
    const u16* ag = A + arow * lda + (scb << 3);
    const u16* bg = B + brow * ldb + (scb << 3);
    u16* asB = As + wave * 2048;                // slab j: +j*512
    u16* bsB = Bs + wave * 2048;

    f32x4 acc[4][4];
#pragma unroll
    for (int i = 0; i < 4; i++)
#pragma unroll
        for (int j = 0; j < 4; j++) {
            acc[i][j][0] = 0.f; acc[i][j][1] = 0.f;
            acc[i][j][2] = 0.f; acc[i][j][3] = 0.f;
        }

    const int fr = lane & 15, fq = lane >> 4;
    const int sw = fr & 7;
    // frag read: row*64 + ((kblk ^ sw) << 3); kblk = kk*4 + fq
    const u16* aRead0 = As + (wm * 64 + fr) * 64 + ((fq ^ sw) << 3);
    const u16* aRead1 = As + (wm * 64 + fr) * 64 + (((4 | fq) ^ sw) << 3);
    const u16* bRead0 = Bs + (wn * 64 + fr) * 64 + ((fq ^ sw) << 3);
    const u16* bRead1 = Bs + (wn * 64 + fr) * 64 + (((4 | fq) ^ sw) << 3);

    const int l8a = 8 * lda, l8b = 8 * ldb;

    for (int k0 = 0; k0 < K; k0 += 64) {
        GLD16(ag + k0,           asB);
        GLD16(ag + k0 + l8a,     asB + 512);
        GLD16(ag + k0 + 2 * l8a, asB + 1024);
        GLD16(ag + k0 + 3 * l8a, asB + 1536);
        GLD16(bg + k0,           bsB);
        GLD16(bg + k0 + l8b,     bsB + 512);
        GLD16(bg + k0 + 2 * l8b, bsB + 1024);
        GLD16(bg + k0 + 3 * l8b, bsB + 1536);
        __syncthreads();

#pragma unroll
        for (int kk = 0; kk < 2; kk++) {
            const u16* ar = kk ? aRead1 : aRead0;
            const u16* br = kk ? bRead1 : bRead0;
            bf16x8 af[4], bfr[4];
#pragma unroll
            for (int i = 0; i < 4; i++) {
                af[i]  = *(const bf16x8*)(ar + i * 16 * 64);
                bfr[i] = *(const bf16x8*)(br + i * 16 * 64);
            }
#pragma unroll
            for (int i = 0; i < 4; i++)
#pragma unroll
                for (int j = 0; j < 4; j++)
                    acc[i][j] = __builtin_amdgcn_mfma_f32_16x16x32_bf16(
                        af[i], bfr[j], acc[i][j], 0, 0, 0);
        }
        __syncthreads();
    }

    // epilogue: C/D layout col=lane&15, row=quad*4+reg
    const int crow0 = bm * 128 + wm * 64 + fq * 4;
    const int ccol0 = bn * 128 + wn * 64 + fr;
#pragma unroll
    for (int i = 0; i < 4; i++) {
#pragma unroll
        for (int r = 0; r < 4; r++) {
            const int row = crow0 + i * 16 + r;
            const float bvr = (bias_mode == 2) ? bf2f(bias[row]) : 0.0f;
#pragma unroll
            for (int j = 0; j < 4; j++) {
                const int col = ccol0 + j * 16;
                const float bv = (bias_mode == 1) ? bf2f(bias[col]) : bvr;
                C[(long long)row * ldc + col] = f2bf(acc[i][j][r] * scale + bv);
            }
        }
    }
}

// ---------------------------------------------------------------------------
// In-place row softmax over 1024 bf16 elements. One wave per row.
// ---------------------------------------------------------------------------
__global__ __launch_bounds__(256) void softmax_kernel(u16* __restrict__ S)
{
    const int tid = threadIdx.x, lane = tid & 63, wave = tid >> 6;
    const long long row = (long long)blockIdx.x * 4 + wave;
    u16* p = S + row * 1024 + lane * 16;
    union { uint4 q[2]; u16 u[16]; } d;
    d.q[0] = *(const uint4*)p;
    d.q[1] = *(const uint4*)(p + 8);
    float x[16];
    float mx = -1e30f;
#pragma unroll
    for (int j = 0; j < 16; j++) { x[j] = bf2f(d.u[j]); mx = fmaxf(mx, x[j]); }
#pragma unroll
    for (int m = 1; m < 64; m <<= 1) mx = fmaxf(mx, __shfl_xor(mx, m));
    float s = 0.f;
#pragma unroll
    for (int j = 0; j < 16; j++) { x[j] = __expf(x[j] - mx); s += x[j]; }
#pragma unroll
    for (int m = 1; m < 64; m <<= 1) s += __shfl_xor(s, m);
    const float inv = 1.0f / s;
#pragma unroll
    for (int j = 0; j < 16; j++) d.u[j] = f2bf(x[j] * inv);
    *(uint4*)p = d.q[0];
    *(uint4*)(p + 8) = d.q[1];
}

// ---------------------------------------------------------------------------
// LayerNorm(obj + I) * g + b -> out (f32 or bf16 per flag). One block per row.
// ---------------------------------------------------------------------------
__global__ __launch_bounds__(256) void ln_kernel(
    const u16* __restrict__ obj, const u16* __restrict__ gam,
    const u16* __restrict__ bet, const u16* __restrict__ I,
    void* __restrict__ outv, long long outOff, const int* __restrict__ flag)
{
    __shared__ float red[8];
    const int tid = threadIdx.x, lane = tid & 63, wave = tid >> 6;
    const long long base = (long long)blockIdx.x * 1024;
    const int c = tid * 4;
    union { uint2 q; u16 u[4]; } ov, iv, gv, bv;
    ov.q = *(const uint2*)(obj + base + c);
    iv.q = *(const uint2*)(I + base + c);
    float x[4], s = 0.f, sq = 0.f;
#pragma unroll
    for (int j = 0; j < 4; j++) {
        x[j] = bf2f(ov.u[j]) + bf2f(iv.u[j]);
        s += x[j]; sq += x[j] * x[j];
    }
#pragma unroll
    for (int m = 1; m < 64; m <<= 1) {
        s += __shfl_xor(s, m);
        sq += __shfl_xor(sq, m);
    }
    if (lane == 0) { red[wave] = s; red[4 + wave] = sq; }
    __syncthreads();
    s = red[0] + red[1] + red[2] + red[3];
    sq = red[4] + red[5] + red[6] + red[7];
    const float mu = s * (1.0f / 1024.0f);
    const float var = fmaxf(sq * (1.0f / 1024.0f) - mu * mu, 0.0f);
    const float rs = rsqrtf(var + 1e-5f);
    gv.q = *(const uint2*)(gam + c);
    bv.q = *(const uint2*)(bet + c);
    float y[4];
#pragma unroll
    for (int j = 0; j < 4; j++)
        y[j] = (x[j] - mu) * rs * bf2f(gv.u[j]) + bf2f(bv.u[j]);
    if (flag[0]) {
        float4 w; w.x = y[0]; w.y = y[1]; w.z = y[2]; w.w = y[3];
        *(float4*)((float*)outv + outOff + base + c) = w;
    } else {
        union { uint2 q; u16 u[4]; } wv;
#pragma unroll
        for (int j = 0; j < 4; j++) wv.u[j] = f2bf(y[j]);
        *(uint2*)((u16*)outv + outOff + base + c) = wv.q;
    }
}

// ---------------------------------------------------------------------------
extern "C" void kernel_launch(void* const* d_in, const int* in_sizes, int n_in,
                              void* d_out, int out_size, void* d_ws, size_t ws_size,
                              hipStream_t stream)
{
    u16* ws = (u16*)d_ws;
    int* flag = (int*)d_ws;              // header: first 64 bytes
    const dim3 blk(256);
    const float scale = 0.03125f;        // 1024^-0.5
    const long long Eobj = 16777216;     // 8*2048*1024
    const long long Ekv  = 8388608;      // 8*1024*1024
    const long long sQ = 2048LL * 1024, sK = 1024LL * 1024;

    detect_kernel<<<dim3(1), blk, 0, stream>>>((const u16*)d_in[0], flag);

    // merged conversion into contiguous region after 64B header
    const size_t wsElems = ws_size / 2;
    ConvArgs ca;
    long long cur = 32;
    u16* cIn[15];
    for (int i = 0; i < 15; i++) {
        ca.src[i] = d_in[i];
        ca.off[i] = cur - 32;
        cIn[i] = ws + cur;
        cur += in_sizes[i];
    }
    ca.off[15] = cur - 32;
    const long long convTotal = cur - 32;
    const bool canConv = wsElems >= (size_t)(32 + convTotal + 8388608 + 32);
    if (canConv) {
        const int grid = (int)((convTotal / 8 + 255) / 256);
        convert_all_kernel<<<dim3(grid), blk, 0, stream>>>(ca, ws + 32, flag);
    } else {
        for (int i = 0; i < 15; i++) cIn[i] = (u16*)d_in[i];
        cur = 32;
    }
    const u16* obj = cIn[0];  const u16* sub = cIn[1];  const u16* scene = cIn[2];
    const u16* W_q = cIn[3];  const u16* b_q = cIn[4];
    const u16* W_sk = cIn[5]; const u16* b_sk = cIn[6];
    const u16* W_sv = cIn[7]; const u16* b_sv = cIn[8];
    const u16* W_ek = cIn[9]; const u16* b_ek = cIn[10];
    const u16* W_ev = cIn[11]; const u16* b_ev = cIn[12];
    const u16* ln_g = cIn[13]; const u16* ln_b = cIn[14];

    const bool planA = wsElems >= (size_t)(cur + Eobj + Ekv + Ekv + Eobj + Eobj);

    if (planA) {
        u16* Q  = ws + cur;
        u16* Kb = Q + Eobj;
        u16* VT = Kb + Ekv;
        u16* S  = VT + Ekv;
        u16* O  = S + Eobj;

        gemm_bt_kernel<<<dim3(8, 128, 1), blk, 0, stream>>>(
            obj, W_q, Q, b_q, 1.0f, 1, 1024, 1024, 1024, 1024, 0, 0, 0);

        for (int a = 0; a < 2; a++) {
            const u16* X  = a ? scene : sub;
            const u16* Wk = a ? W_ek : W_sk;
            const u16* bk = a ? b_ek : b_sk;
            const u16* Wv = a ? W_ev : W_sv;
            const u16* bv = a ? b_ev : b_sv;

            gemm_bt_kernel<<<dim3(8, 64, 1), blk, 0, stream>>>(
                X, Wk, Kb, bk, 1.0f, 1, 1024, 1024, 1024, 1024, 0, 0, 0);
            // VT[p][z*1024+s] = V_z[s][p] = Wv[p,:].X_z[s,:] + bv[p]
            gemm_bt_kernel<<<dim3(64, 8, 1), blk, 0, stream>>>(
                Wv, X, VT, bv, 1.0f, 2, 1024, 1024, 8192, 1024, 0, 0, 0);
            gemm_bt_kernel<<<dim3(8, 16, 8), blk, 0, stream>>>(
                Q, Kb, S, nullptr, scale, 0, 1024, 1024, 1024, 1024, sQ, sK, sQ);
            softmax_kernel<<<dim3(4096), blk, 0, stream>>>(S);
            gemm_bt_kernel<<<dim3(8, 16, 8), blk, 0, stream>>>(
                S, VT, O, nullptr, 1.0f, 0, 1024, 8192, 1024, 1024, sQ, 1024, sQ);
            ln_kernel<<<dim3(16384), blk, 0, stream>>>(
                obj, ln_g, ln_b, O, d_out, (long long)a * Eobj, flag);
        }
    } else {
        // per-batch fallback: 8.39M elems of pipeline scratch
        u16* Qb = ws + cur;              // 2M
        u16* Kb = Qb + 2097152;          // 1M
        u16* VT = Kb + 1048576;          // 1M
        u16* S  = VT + 1048576;          // 2M
        u16* O  = S + 2097152;           // 2M

        for (int a = 0; a < 2; a++) {
            const u16* X  = a ? scene : sub;
            const u16* Wk = a ? W_ek : W_sk;
            const u16* bk = a ? b_ek : b_sk;
            const u16* Wv = a ? W_ev : W_sv;
            const u16* bv = a ? b_ev : b_sv;

            for (int z = 0; z < 8; z++) {
                const u16* objz = obj + (long long)z * sQ;
                const u16* Xz   = X + (long long)z * sK;
                gemm_bt_kernel<<<dim3(8, 16, 1), blk, 0, stream>>>(
                    objz, W_q, Qb, b_q, 1.0f, 1, 1024, 1024, 1024, 1024, 0, 0, 0);
                gemm_bt_kernel<<<dim3(8, 8, 1), blk, 0, stream>>>(
                    Xz, Wk, Kb, bk, 1.0f, 1, 1024, 1024, 1024, 1024, 0, 0, 0);
                gemm_bt_kernel<<<dim3(8, 8, 1), blk, 0, stream>>>(
                    Wv, Xz, VT, bv, 1.0f, 2, 1024, 1024, 1024, 1024, 0, 0, 0);
                gemm_bt_kernel<<<dim3(8, 16, 1), blk, 0, stream>>>(
                    Qb, Kb, S, nullptr, scale, 0, 1024, 1024, 1024, 1024, 0, 0, 0);
                softmax_kernel<<<dim3(512), blk, 0, stream>>>(S);
                gemm_bt_kernel<<<dim3(8, 16, 1), blk, 0, stream>>>(
                    S, VT, O, nullptr, 1.0f, 0, 1024, 1024, 1024, 1024, 0, 0, 0);
                ln_kernel<<<dim3(2048), blk, 0, stream>>>(
                    objz, ln_g, ln_b, O, d_out,
                    (long long)a * Eobj + (long long)z * sQ, flag);
            }
        }
    }

    (void)n_in; (void)out_size;
}